// Round 1
// baseline (613.972 us; speedup 1.0000x reference)
//
#include <hip/hip_runtime.h>

// GAT (3-layer) on MI355X. N=50000 nodes, E=800000 edges, D=64, H=2/2/1.
// Pipeline per launch: build CSR by dst -> embedding gather ->
// per layer: GEMM (fp32, LDS-tiled) -> el/er (wave dot) -> edge-softmax aggregate.

__device__ __forceinline__ float lrelu(float x){ return x >= 0.f ? x : 0.2f*x; }

__global__ void k_zero_i32(int* __restrict__ p, int n){
  int i = blockIdx.x*blockDim.x + threadIdx.x;
  if (i < n) p[i] = 0;
}

__global__ void k_gather_h0(const int* __restrict__ feat, const float* __restrict__ fv,
                            const float* __restrict__ emb, float* __restrict__ h0, int N){
  int t = blockIdx.x*blockDim.x + threadIdx.x;
  int n = t >> 6, d = t & 63;
  if (n >= N) return;
  h0[t] = emb[feat[n]*64 + d] * fv[n];
}

__global__ void k_hist(const int* __restrict__ dst, int* __restrict__ counts, int E){
  int i = blockIdx.x*blockDim.x + threadIdx.x;
  if (i < E) atomicAdd(&counts[dst[i]], 1);
}

__global__ void k_scan_local(const int* __restrict__ counts, int* __restrict__ row_ptr,
                             int* __restrict__ bsum, int N){
  __shared__ int s[256];
  int t = threadIdx.x, g = blockIdx.x*256 + t;
  int v = (g < N) ? counts[g] : 0;
  s[t] = v; __syncthreads();
  #pragma unroll
  for (int off = 1; off < 256; off <<= 1){
    int x = 0;
    if (t >= off) x = s[t-off];
    __syncthreads();
    s[t] += x;
    __syncthreads();
  }
  if (g < N) row_ptr[g+1] = s[t];
  if (g == 0 && t == 0) row_ptr[0] = 0;
  if (t == 255) bsum[blockIdx.x] = s[255];
}

__global__ void k_scan_top(int* __restrict__ bsum, int nb){
  __shared__ int s[256];
  int t = threadIdx.x;
  int v = (t < nb) ? bsum[t] : 0;
  s[t] = v; __syncthreads();
  #pragma unroll
  for (int off = 1; off < 256; off <<= 1){
    int x = 0;
    if (t >= off) x = s[t-off];
    __syncthreads();
    s[t] += x;
    __syncthreads();
  }
  if (t < nb) bsum[t] = s[t] - v;  // exclusive block offsets
}

__global__ void k_scan_fix(int* __restrict__ row_ptr, const int* __restrict__ bsum, int N){
  int g = blockIdx.x*256 + threadIdx.x;
  if (g < N && blockIdx.x > 0) row_ptr[g+1] += bsum[blockIdx.x];
}

__global__ void k_scatter(const int* __restrict__ src, const int* __restrict__ dst,
                          const int* __restrict__ row_ptr, int* __restrict__ cursor,
                          int* __restrict__ ssrc, int E){
  int i = blockIdx.x*blockDim.x + threadIdx.x;
  if (i >= E) return;
  int d = dst[i];
  int pos = atomicAdd(&cursor[d], 1);
  ssrc[row_ptr[d] + pos] = src[i];
}

// fh[N][128] = h[N][IN] @ [Wa | Wb]  (Wa cols 0..63, Wb cols 64..127).
// Block: 256 threads = 4 waves; each wave: 8 rows x 128 cols (2 cols/lane).
__global__ __launch_bounds__(256) void k_gemm(
    const float* __restrict__ h, int ldh, int IN,
    const float* __restrict__ Wa, const float* __restrict__ Wb, int ldw,
    float* __restrict__ fh, int N){
  __shared__ float hs[128][33];     // [k][r], +1 pad: conflict-free staging writes
  __shared__ float2 Wp[64][64];     // [kk][lane] = (W[:, lane], W[:, 64+lane])
  int t = threadIdx.x;
  int lane = t & 63, wid = t >> 6;
  int row0 = blockIdx.x * 32;
  int tot = 32 * IN;
  for (int id = t; id < tot; id += 256){
    int r = id / IN, k = id - r*IN;
    int row = row0 + r;
    hs[k][r] = (row < N) ? h[row*ldh + k] : 0.f;
  }
  float2 acc[8];
  #pragma unroll
  for (int j = 0; j < 8; j++) acc[j] = make_float2(0.f, 0.f);
  for (int kb = 0; kb < IN; kb += 64){
    __syncthreads();
    for (int id = t; id < 64*64; id += 256){
      int kk = id >> 6, l = id & 63;
      int k = kb + kk;
      Wp[kk][l] = make_float2(Wa[k*ldw + l], Wb[k*ldw + l]);
    }
    __syncthreads();
    #pragma unroll 8
    for (int kk = 0; kk < 64; kk++){
      float2 wv = Wp[kk][lane];
      int k = kb + kk;
      #pragma unroll
      for (int j = 0; j < 8; j++){
        float hv = hs[k][wid*8 + j];      // broadcast read
        acc[j].x += hv * wv.x;
        acc[j].y += hv * wv.y;
      }
    }
  }
  #pragma unroll
  for (int j = 0; j < 8; j++){
    int row = row0 + wid*8 + j;
    if (row < N){
      fh[row*128 + lane]      = acc[j].x;
      fh[row*128 + 64 + lane] = acc[j].y;
    }
  }
}

// elr[n][4] = {el_h0, el_h1, er_h0, er_h1}; one wave per node.
__global__ void k_elr(const float* __restrict__ fh, const float* __restrict__ al,
                      const float* __restrict__ ar, int H, float* __restrict__ elr, int N){
  int t = blockIdx.x*blockDim.x + threadIdx.x;
  int lane = t & 63, n = t >> 6;
  if (n >= N) return;
  float pel = 0.f, per = 0.f;
  if (lane*2 < H*64){
    float2 v = *(const float2*)(fh + n*128 + lane*2);
    float2 a = ((const float2*)al)[lane];
    float2 r = ((const float2*)ar)[lane];
    pel = v.x*a.x + v.y*a.y;
    per = v.x*r.x + v.y*r.y;
  }
  #pragma unroll
  for (int off = 16; off >= 1; off >>= 1){  // reduce within 32-lane halves (= heads)
    pel += __shfl_xor(pel, off, 64);
    per += __shfl_xor(per, off, 64);
  }
  if (lane == 0)  { elr[n*4+0] = pel; elr[n*4+2] = per; }
  if (lane == 32) { elr[n*4+1] = pel; elr[n*4+3] = per; }
}

// One wave per dst node: 3 passes (max, denom, weighted accumulate).
__global__ __launch_bounds__(256) void k_agg(
    const float* __restrict__ fh, const float* __restrict__ elr,
    const int* __restrict__ row_ptr, const int* __restrict__ ssrc,
    const float* __restrict__ bias, const float* __restrict__ res,
    int H, int act, int res_from_fh,
    float* __restrict__ out, int out_ld, int N){
  int lane = threadIdx.x & 63, wid = threadIdx.x >> 6;
  int n = blockIdx.x*4 + wid;
  if (n >= N) return;
  int beg = row_ptr[n], end = row_ptr[n+1];
  float er0 = elr[n*4+2], er1 = elr[n*4+3];

  float m0 = -1e30f, m1 = -1e30f;
  for (int i = beg + lane; i < end; i += 64){
    int s = ssrc[i];
    float2 el = *(const float2*)(elr + s*4);
    m0 = fmaxf(m0, lrelu(el.x + er0));
    m1 = fmaxf(m1, lrelu(el.y + er1));
  }
  #pragma unroll
  for (int off = 32; off >= 1; off >>= 1){
    m0 = fmaxf(m0, __shfl_xor(m0, off, 64));
    m1 = fmaxf(m1, __shfl_xor(m1, off, 64));
  }
  float d0 = 0.f, d1 = 0.f;
  for (int i = beg + lane; i < end; i += 64){
    int s = ssrc[i];
    float2 el = *(const float2*)(elr + s*4);
    d0 += __expf(lrelu(el.x + er0) - m0);
    d1 += __expf(lrelu(el.y + er1) - m1);
  }
  #pragma unroll
  for (int off = 32; off >= 1; off >>= 1){
    d0 += __shfl_xor(d0, off, 64);
    d1 += __shfl_xor(d1, off, 64);
  }
  float rd0 = d0 > 0.f ? 1.f/d0 : 0.f;
  float rd1 = d1 > 0.f ? 1.f/d1 : 0.f;

  float ax = 0.f, ay = 0.f;
  for (int base = beg; base < end; base += 64){
    int i = base + lane;
    int s = 0; float a0 = 0.f, a1 = 0.f;
    if (i < end){
      s = ssrc[i];
      float2 el = *(const float2*)(elr + s*4);
      a0 = __expf(lrelu(el.x + er0) - m0) * rd0;
      a1 = __expf(lrelu(el.y + er1) - m1) * rd1;
    }
    int cnt = min(64, end - base);
    for (int j = 0; j < cnt; j++){
      int   sj  = __shfl(s,  j, 64);
      float aj0 = __shfl(a0, j, 64);
      float aj1 = __shfl(a1, j, 64);
      if (H == 2){
        float2 v = *(const float2*)(fh + sj*128 + lane*2);
        float aj = (lane < 32) ? aj0 : aj1;   // cols 2l,2l+1: head = lane/32
        ax += v.x*aj; ay += v.y*aj;
      } else {
        ax += fh[sj*128 + lane] * aj0;
      }
    }
  }
  if (H == 2){
    int c0 = lane*2;
    float o0 = ax + bias[c0], o1 = ay + bias[c0+1];
    if (res){ o0 += res[n*128 + c0]; o1 += res[n*128 + c0+1]; }
    if (act){ o0 = o0 > 0.f ? o0 : expm1f(o0); o1 = o1 > 0.f ? o1 : expm1f(o1); }
    *(float2*)(out + n*out_ld + c0) = make_float2(o0, o1);
  } else {
    float o = ax + bias[lane];
    if (res_from_fh) o += fh[n*128 + 64 + lane];
    out[n*out_ld + lane] = o;
  }
}

extern "C" void kernel_launch(void* const* d_in, const int* in_sizes, int n_in,
                              void* d_out, int out_size, void* d_ws, size_t ws_size,
                              hipStream_t stream) {
  const int*   feat = (const int*)  d_in[0];
  const float* fv   = (const float*)d_in[1];
  const int*   src  = (const int*)  d_in[2];
  const int*   dst  = (const int*)  d_in[3];
  const float* emb  = (const float*)d_in[4];
  const float* W0   = (const float*)d_in[5];
  const float* al0  = (const float*)d_in[6];
  const float* ar0  = (const float*)d_in[7];
  const float* b0   = (const float*)d_in[8];
  const float* W1   = (const float*)d_in[9];
  const float* al1  = (const float*)d_in[10];
  const float* ar1  = (const float*)d_in[11];
  const float* b1   = (const float*)d_in[12];
  const float* W2   = (const float*)d_in[13];
  const float* al2  = (const float*)d_in[14];
  const float* ar2  = (const float*)d_in[15];
  const float* b2   = (const float*)d_in[16];
  const float* rW2  = (const float*)d_in[17];
  const int N = in_sizes[0] / 8;   // 50000
  const int E = in_sizes[2];       // 800000

  size_t off = 0;
  auto alloc = [&](size_t bytes) -> void* {
    void* p = (char*)d_ws + off;
    off = (off + bytes + 255) & ~(size_t)255;
    return p;
  };
  float* P1     = (float*)alloc((size_t)N*128*sizeof(float));
  float* P2     = (float*)alloc((size_t)N*128*sizeof(float));
  float* P3     = (float*)alloc((size_t)N*128*sizeof(float));
  float* elr    = (float*)alloc((size_t)N*4*sizeof(float));
  int* row_ptr  = (int*)alloc((size_t)(N+1)*sizeof(int));
  int* counts   = (int*)alloc((size_t)2*N*sizeof(int));
  int* cursor   = counts + N;
  int* ssrc     = (int*)alloc((size_t)E*sizeof(int));
  int* bsum     = (int*)alloc(256*sizeof(int));
  float* h0     = P3;   // h0 (N*64) aliases P3; dead before P3 is written as h2

  int nb1 = (N + 255) / 256;
  // CSR build
  k_zero_i32<<<(2*N + 255)/256, 256, 0, stream>>>(counts, 2*N);
  k_hist<<<(E + 255)/256, 256, 0, stream>>>(dst, counts, E);
  k_scan_local<<<nb1, 256, 0, stream>>>(counts, row_ptr, bsum, N);
  k_scan_top<<<1, 256, 0, stream>>>(bsum, nb1);
  k_scan_fix<<<nb1, 256, 0, stream>>>(row_ptr, bsum, N);
  k_scatter<<<(E + 255)/256, 256, 0, stream>>>(src, dst, row_ptr, cursor, ssrc, E);
  // embedding gather (batch row 0 only)
  k_gather_h0<<<(N*64 + 255)/256, 256, 0, stream>>>(feat, fv, emb, h0, N);

  int gt = (N + 31)/32;
  int nagg = (N + 3)/4;
  // layer 0: in=64, H=2, no residual, elu
  k_gemm<<<gt, 256, 0, stream>>>(h0, 64, 64, W0, W0 + 64, 128, P1, N);
  k_elr<<<nagg, 256, 0, stream>>>(P1, al0, ar0, 2, elr, N);
  k_agg<<<nagg, 256, 0, stream>>>(P1, elr, row_ptr, ssrc, b0, nullptr, 2, 1, 0, P2, 128, N);
  // layer 1: in=128, H=2, identity residual, elu
  k_gemm<<<gt, 256, 0, stream>>>(P2, 128, 128, W1, W1 + 64, 128, P1, N);
  k_elr<<<nagg, 256, 0, stream>>>(P1, al1, ar1, 2, elr, N);
  k_agg<<<nagg, 256, 0, stream>>>(P1, elr, row_ptr, ssrc, b1, P2, 2, 1, 0, P3, 128, N);
  // layer 2: in=128, H=1, projected residual (fh cols 64..127 = h@resW2), no act
  k_gemm<<<gt, 256, 0, stream>>>(P3, 128, 128, W2, rW2, 64, P1, N);
  k_elr<<<nagg, 256, 0, stream>>>(P1, al2, ar2, 1, elr, N);
  k_agg<<<nagg, 256, 0, stream>>>(P1, elr, row_ptr, ssrc, b2, nullptr, 1, 0, 1, (float*)d_out, 64, N);
}

// Round 2
// 587.334 us; speedup vs baseline: 1.0454x; 1.0454x over previous
//
#include <hip/hip_runtime.h>

// GAT (3-layer) on MI355X. N=50000 nodes, E=800000 edges, D=64, H=2/2/1.
// R2: fh stored as packed bf16 (halves gather traffic + footprint -> better L2),
//     online-softmax merges max+denom passes in k_agg.

__device__ __forceinline__ float lrelu(float x){ return x >= 0.f ? x : 0.2f*x; }

__device__ __forceinline__ unsigned short f2bf(float f){   // RNE round
  unsigned int u = __float_as_uint(f);
  u += 0x7fffu + ((u >> 16) & 1u);
  return (unsigned short)(u >> 16);
}
__device__ __forceinline__ float bf2f(unsigned short u){
  return __uint_as_float((unsigned int)u << 16);
}

__global__ void k_zero_i32(int* __restrict__ p, int n){
  int i = blockIdx.x*blockDim.x + threadIdx.x;
  if (i < n) p[i] = 0;
}

__global__ void k_gather_h0(const int* __restrict__ feat, const float* __restrict__ fv,
                            const float* __restrict__ emb, float* __restrict__ h0, int N){
  int t = blockIdx.x*blockDim.x + threadIdx.x;
  int n = t >> 6, d = t & 63;
  if (n >= N) return;
  h0[t] = emb[feat[n]*64 + d] * fv[n];
}

__global__ void k_hist(const int* __restrict__ dst, int* __restrict__ counts, int E){
  int i = blockIdx.x*blockDim.x + threadIdx.x;
  if (i < E) atomicAdd(&counts[dst[i]], 1);
}

__global__ void k_scan_local(const int* __restrict__ counts, int* __restrict__ row_ptr,
                             int* __restrict__ bsum, int N){
  __shared__ int s[256];
  int t = threadIdx.x, g = blockIdx.x*256 + t;
  int v = (g < N) ? counts[g] : 0;
  s[t] = v; __syncthreads();
  #pragma unroll
  for (int off = 1; off < 256; off <<= 1){
    int x = 0;
    if (t >= off) x = s[t-off];
    __syncthreads();
    s[t] += x;
    __syncthreads();
  }
  if (g < N) row_ptr[g+1] = s[t];
  if (g == 0 && t == 0) row_ptr[0] = 0;
  if (t == 255) bsum[blockIdx.x] = s[255];
}

__global__ void k_scan_top(int* __restrict__ bsum, int nb){
  __shared__ int s[256];
  int t = threadIdx.x;
  int v = (t < nb) ? bsum[t] : 0;
  s[t] = v; __syncthreads();
  #pragma unroll
  for (int off = 1; off < 256; off <<= 1){
    int x = 0;
    if (t >= off) x = s[t-off];
    __syncthreads();
    s[t] += x;
    __syncthreads();
  }
  if (t < nb) bsum[t] = s[t] - v;  // exclusive block offsets
}

__global__ void k_scan_fix(int* __restrict__ row_ptr, const int* __restrict__ bsum, int N){
  int g = blockIdx.x*256 + threadIdx.x;
  if (g < N && blockIdx.x > 0) row_ptr[g+1] += bsum[blockIdx.x];
}

__global__ void k_scatter(const int* __restrict__ src, const int* __restrict__ dst,
                          const int* __restrict__ row_ptr, int* __restrict__ cursor,
                          int* __restrict__ ssrc, int E){
  int i = blockIdx.x*blockDim.x + threadIdx.x;
  if (i >= E) return;
  int d = dst[i];
  int pos = atomicAdd(&cursor[d], 1);
  ssrc[row_ptr[d] + pos] = src[i];
}

// fh[N][128](bf16) = h[N][IN] @ [Wa | Wb]. Accumulate fp32, store bf16.
__global__ __launch_bounds__(256) void k_gemm(
    const float* __restrict__ h, int ldh, int IN,
    const float* __restrict__ Wa, const float* __restrict__ Wb, int ldw,
    unsigned short* __restrict__ fhb, int N){
  __shared__ float hs[128][33];
  __shared__ float2 Wp[64][64];
  int t = threadIdx.x;
  int lane = t & 63, wid = t >> 6;
  int row0 = blockIdx.x * 32;
  int tot = 32 * IN;
  for (int id = t; id < tot; id += 256){
    int r = id / IN, k = id - r*IN;
    int row = row0 + r;
    hs[k][r] = (row < N) ? h[row*ldh + k] : 0.f;
  }
  float2 acc[8];
  #pragma unroll
  for (int j = 0; j < 8; j++) acc[j] = make_float2(0.f, 0.f);
  for (int kb = 0; kb < IN; kb += 64){
    __syncthreads();
    for (int id = t; id < 64*64; id += 256){
      int kk = id >> 6, l = id & 63;
      int k = kb + kk;
      Wp[kk][l] = make_float2(Wa[k*ldw + l], Wb[k*ldw + l]);
    }
    __syncthreads();
    #pragma unroll 8
    for (int kk = 0; kk < 64; kk++){
      float2 wv = Wp[kk][lane];
      int k = kb + kk;
      #pragma unroll
      for (int j = 0; j < 8; j++){
        float hv = hs[k][wid*8 + j];
        acc[j].x += hv * wv.x;
        acc[j].y += hv * wv.y;
      }
    }
  }
  #pragma unroll
  for (int j = 0; j < 8; j++){
    int row = row0 + wid*8 + j;
    if (row < N){
      fhb[(size_t)row*128 + lane]      = f2bf(acc[j].x);
      fhb[(size_t)row*128 + 64 + lane] = f2bf(acc[j].y);
    }
  }
}

// elr[n][4] = {el_h0, el_h1, er_h0, er_h1}; one wave per node; fh in bf16.
__global__ void k_elr(const unsigned short* __restrict__ fhb, const float* __restrict__ al,
                      const float* __restrict__ ar, int H, float* __restrict__ elr, int N){
  int t = blockIdx.x*blockDim.x + threadIdx.x;
  int lane = t & 63, n = t >> 6;
  if (n >= N) return;
  float pel = 0.f, per = 0.f;
  if (lane*2 < H*64){
    unsigned int w = ((const unsigned int*)(fhb + (size_t)n*128))[lane];  // cols 2l,2l+1
    float vx = bf2f((unsigned short)(w & 0xffffu));
    float vy = bf2f((unsigned short)(w >> 16));
    float2 a = ((const float2*)al)[lane];
    float2 r = ((const float2*)ar)[lane];
    pel = vx*a.x + vy*a.y;
    per = vx*r.x + vy*r.y;
  }
  #pragma unroll
  for (int off = 16; off >= 1; off >>= 1){  // reduce within 32-lane halves (= heads)
    pel += __shfl_xor(pel, off, 64);
    per += __shfl_xor(per, off, 64);
  }
  if (lane == 0)  { elr[n*4+0] = pel; elr[n*4+2] = per; }
  if (lane == 32) { elr[n*4+1] = pel; elr[n*4+3] = per; }
}

// One wave per dst node. Pass 1: online softmax (m,d). Pass 2: weighted gather (bf16).
__global__ __launch_bounds__(256) void k_agg(
    const unsigned short* __restrict__ fhb, const float* __restrict__ elr,
    const int* __restrict__ row_ptr, const int* __restrict__ ssrc,
    const float* __restrict__ bias, const float* __restrict__ res,
    int H, int act, int res_from_fh,
    float* __restrict__ out, int out_ld, int N){
  int lane = threadIdx.x & 63, wid = threadIdx.x >> 6;
  int n = blockIdx.x*4 + wid;
  if (n >= N) return;
  int beg = row_ptr[n], end = row_ptr[n+1];
  float er0 = elr[n*4+2], er1 = elr[n*4+3];

  // pass 1: per-lane online softmax, then cross-lane merge
  float m0 = -1e30f, m1 = -1e30f, d0 = 0.f, d1 = 0.f;
  for (int i = beg + lane; i < end; i += 64){
    int s = ssrc[i];
    float2 el = *(const float2*)(elr + s*4);
    float e0 = lrelu(el.x + er0), e1 = lrelu(el.y + er1);
    float nm0 = fmaxf(m0, e0);
    d0 = d0*__expf(m0 - nm0) + __expf(e0 - nm0); m0 = nm0;
    float nm1 = fmaxf(m1, e1);
    d1 = d1*__expf(m1 - nm1) + __expf(e1 - nm1); m1 = nm1;
  }
  #pragma unroll
  for (int off = 32; off >= 1; off >>= 1){
    float mo0 = __shfl_xor(m0, off, 64), do0 = __shfl_xor(d0, off, 64);
    float nm0 = fmaxf(m0, mo0);
    d0 = d0*__expf(m0 - nm0) + do0*__expf(mo0 - nm0); m0 = nm0;
    float mo1 = __shfl_xor(m1, off, 64), do1 = __shfl_xor(d1, off, 64);
    float nm1 = fmaxf(m1, mo1);
    d1 = d1*__expf(m1 - nm1) + do1*__expf(mo1 - nm1); m1 = nm1;
  }
  float rd0 = d0 > 0.f ? 1.f/d0 : 0.f;
  float rd1 = d1 > 0.f ? 1.f/d1 : 0.f;

  // pass 2: alpha-weighted gather of bf16 rows
  float ax = 0.f, ay = 0.f;
  for (int base = beg; base < end; base += 64){
    int i = base + lane;
    int s = 0; float a0 = 0.f, a1 = 0.f;
    if (i < end){
      s = ssrc[i];
      float2 el = *(const float2*)(elr + s*4);
      a0 = __expf(lrelu(el.x + er0) - m0) * rd0;
      a1 = __expf(lrelu(el.y + er1) - m1) * rd1;
    }
    int cnt = min(64, end - base);
    for (int j = 0; j < cnt; j++){
      int   sj  = __shfl(s,  j, 64);
      float aj0 = __shfl(a0, j, 64);
      float aj1 = __shfl(a1, j, 64);
      if (H == 2){
        unsigned int w = ((const unsigned int*)(fhb + (size_t)sj*128))[lane]; // cols 2l,2l+1
        float vx = bf2f((unsigned short)(w & 0xffffu));
        float vy = bf2f((unsigned short)(w >> 16));
        float aj = (lane < 32) ? aj0 : aj1;   // head = (2*lane)/64
        ax += vx*aj; ay += vy*aj;
      } else {
        ax += bf2f(fhb[(size_t)sj*128 + lane]) * aj0;
      }
    }
  }
  if (H == 2){
    int c0 = lane*2;
    float o0 = ax + bias[c0], o1 = ay + bias[c0+1];
    if (res){ o0 += res[n*128 + c0]; o1 += res[n*128 + c0+1]; }
    if (act){ o0 = o0 > 0.f ? o0 : expm1f(o0); o1 = o1 > 0.f ? o1 : expm1f(o1); }
    *(float2*)(out + n*out_ld + c0) = make_float2(o0, o1);
  } else {
    float o = ax + bias[lane];
    if (res_from_fh) o += bf2f(fhb[(size_t)n*128 + 64 + lane]);
    out[n*out_ld + lane] = o;
  }
}

extern "C" void kernel_launch(void* const* d_in, const int* in_sizes, int n_in,
                              void* d_out, int out_size, void* d_ws, size_t ws_size,
                              hipStream_t stream) {
  const int*   feat = (const int*)  d_in[0];
  const float* fv   = (const float*)d_in[1];
  const int*   src  = (const int*)  d_in[2];
  const int*   dst  = (const int*)  d_in[3];
  const float* emb  = (const float*)d_in[4];
  const float* W0   = (const float*)d_in[5];
  const float* al0  = (const float*)d_in[6];
  const float* ar0  = (const float*)d_in[7];
  const float* b0   = (const float*)d_in[8];
  const float* W1   = (const float*)d_in[9];
  const float* al1  = (const float*)d_in[10];
  const float* ar1  = (const float*)d_in[11];
  const float* b1   = (const float*)d_in[12];
  const float* W2   = (const float*)d_in[13];
  const float* al2  = (const float*)d_in[14];
  const float* ar2  = (const float*)d_in[15];
  const float* b2   = (const float*)d_in[16];
  const float* rW2  = (const float*)d_in[17];
  const int N = in_sizes[0] / 8;   // 50000
  const int E = in_sizes[2];       // 800000

  size_t off = 0;
  auto alloc = [&](size_t bytes) -> void* {
    void* p = (char*)d_ws + off;
    off = (off + bytes + 255) & ~(size_t)255;
    return p;
  };
  unsigned short* P1 = (unsigned short*)alloc((size_t)N*128*sizeof(unsigned short)); // fh bf16
  float* P2     = (float*)alloc((size_t)N*128*sizeof(float));
  float* P3     = (float*)alloc((size_t)N*128*sizeof(float));
  float* elr    = (float*)alloc((size_t)N*4*sizeof(float));
  int* row_ptr  = (int*)alloc((size_t)(N+1)*sizeof(int));
  int* counts   = (int*)alloc((size_t)2*N*sizeof(int));
  int* cursor   = counts + N;
  int* ssrc     = (int*)alloc((size_t)E*sizeof(int));
  int* bsum     = (int*)alloc(256*sizeof(int));
  float* h0     = P3;   // h0 (N*64) aliases P3; dead before P3 is written as h2

  int nb1 = (N + 255) / 256;
  // CSR build
  k_zero_i32<<<(2*N + 255)/256, 256, 0, stream>>>(counts, 2*N);
  k_hist<<<(E + 255)/256, 256, 0, stream>>>(dst, counts, E);
  k_scan_local<<<nb1, 256, 0, stream>>>(counts, row_ptr, bsum, N);
  k_scan_top<<<1, 256, 0, stream>>>(bsum, nb1);
  k_scan_fix<<<nb1, 256, 0, stream>>>(row_ptr, bsum, N);
  k_scatter<<<(E + 255)/256, 256, 0, stream>>>(src, dst, row_ptr, cursor, ssrc, E);
  // embedding gather (batch row 0 only)
  k_gather_h0<<<(N*64 + 255)/256, 256, 0, stream>>>(feat, fv, emb, h0, N);

  int gt = (N + 31)/32;
  int nagg = (N + 3)/4;
  // layer 0: in=64, H=2, no residual, elu
  k_gemm<<<gt, 256, 0, stream>>>(h0, 64, 64, W0, W0 + 64, 128, P1, N);
  k_elr<<<nagg, 256, 0, stream>>>(P1, al0, ar0, 2, elr, N);
  k_agg<<<nagg, 256, 0, stream>>>(P1, elr, row_ptr, ssrc, b0, nullptr, 2, 1, 0, P2, 128, N);
  // layer 1: in=128, H=2, identity residual, elu
  k_gemm<<<gt, 256, 0, stream>>>(P2, 128, 128, W1, W1 + 64, 128, P1, N);
  k_elr<<<nagg, 256, 0, stream>>>(P1, al1, ar1, 2, elr, N);
  k_agg<<<nagg, 256, 0, stream>>>(P1, elr, row_ptr, ssrc, b1, P2, 2, 1, 0, P3, 128, N);
  // layer 2: in=128, H=1, projected residual (fh cols 64..127 = h@resW2), no act
  k_gemm<<<gt, 256, 0, stream>>>(P3, 128, 128, W2, rW2, 64, P1, N);
  k_elr<<<nagg, 256, 0, stream>>>(P1, al2, ar2, 1, elr, N);
  k_agg<<<nagg, 256, 0, stream>>>(P1, elr, row_ptr, ssrc, b2, nullptr, 1, 0, 1, (float*)d_out, 64, N);
}

// Round 3
// 487.670 us; speedup vs baseline: 1.2590x; 1.2044x over previous
//
#include <hip/hip_runtime.h>

// GAT (3-layer) on MI355X. N=50000 nodes, E=800000 edges, D=64, H=2/2/1.
// R3: k_agg gather uses readlane (uniform broadcast -> SGPR) + 8-deep load
//     pipelining to kill the per-edge latency chain; k_gemm hs tile
//     transposed to [r][k] for ds_read_b128.

__device__ __forceinline__ float lrelu(float x){ return x >= 0.f ? x : 0.2f*x; }

__device__ __forceinline__ unsigned short f2bf(float f){   // RNE round
  unsigned int u = __float_as_uint(f);
  u += 0x7fffu + ((u >> 16) & 1u);
  return (unsigned short)(u >> 16);
}
__device__ __forceinline__ float bf2f(unsigned short u){
  return __uint_as_float((unsigned int)u << 16);
}
__device__ __forceinline__ float rl_f(float v, int l){
  return __int_as_float(__builtin_amdgcn_readlane(__float_as_int(v), l));
}

__global__ void k_zero_i32(int* __restrict__ p, int n){
  int i = blockIdx.x*blockDim.x + threadIdx.x;
  if (i < n) p[i] = 0;
}

__global__ void k_gather_h0(const int* __restrict__ feat, const float* __restrict__ fv,
                            const float* __restrict__ emb, float* __restrict__ h0, int N){
  int t = blockIdx.x*blockDim.x + threadIdx.x;
  int n = t >> 6, d = t & 63;
  if (n >= N) return;
  h0[t] = emb[feat[n]*64 + d] * fv[n];
}

__global__ void k_hist(const int* __restrict__ dst, int* __restrict__ counts, int E){
  int i = blockIdx.x*blockDim.x + threadIdx.x;
  if (i < E) atomicAdd(&counts[dst[i]], 1);
}

__global__ void k_scan_local(const int* __restrict__ counts, int* __restrict__ row_ptr,
                             int* __restrict__ bsum, int N){
  __shared__ int s[256];
  int t = threadIdx.x, g = blockIdx.x*256 + t;
  int v = (g < N) ? counts[g] : 0;
  s[t] = v; __syncthreads();
  #pragma unroll
  for (int off = 1; off < 256; off <<= 1){
    int x = 0;
    if (t >= off) x = s[t-off];
    __syncthreads();
    s[t] += x;
    __syncthreads();
  }
  if (g < N) row_ptr[g+1] = s[t];
  if (g == 0 && t == 0) row_ptr[0] = 0;
  if (t == 255) bsum[blockIdx.x] = s[255];
}

__global__ void k_scan_top(int* __restrict__ bsum, int nb){
  __shared__ int s[256];
  int t = threadIdx.x;
  int v = (t < nb) ? bsum[t] : 0;
  s[t] = v; __syncthreads();
  #pragma unroll
  for (int off = 1; off < 256; off <<= 1){
    int x = 0;
    if (t >= off) x = s[t-off];
    __syncthreads();
    s[t] += x;
    __syncthreads();
  }
  if (t < nb) bsum[t] = s[t] - v;  // exclusive block offsets
}

__global__ void k_scan_fix(int* __restrict__ row_ptr, const int* __restrict__ bsum, int N){
  int g = blockIdx.x*256 + threadIdx.x;
  if (g < N && blockIdx.x > 0) row_ptr[g+1] += bsum[blockIdx.x];
}

__global__ void k_scatter(const int* __restrict__ src, const int* __restrict__ dst,
                          const int* __restrict__ row_ptr, int* __restrict__ cursor,
                          int* __restrict__ ssrc, int E){
  int i = blockIdx.x*blockDim.x + threadIdx.x;
  if (i >= E) return;
  int d = dst[i];
  int pos = atomicAdd(&cursor[d], 1);
  ssrc[row_ptr[d] + pos] = src[i];
}

// fh[N][128](bf16) = h[N][IN] @ [Wa | Wb]. Accumulate fp32, store bf16.
__global__ __launch_bounds__(256) void k_gemm(
    const float* __restrict__ h, int ldh, int IN,
    const float* __restrict__ Wa, const float* __restrict__ Wb, int ldw,
    unsigned short* __restrict__ fhb, int N){
  __shared__ float hs[32][132];     // [r][k]: b128 reads along k; row stride 132 (16B-aligned)
  __shared__ float2 Wp[64][64];     // [kk][lane] = (W[:, lane], W[:, 64+lane])
  int t = threadIdx.x;
  int lane = t & 63, wid = t >> 6;
  int row0 = blockIdx.x * 32;
  int tot = 32 * IN;
  for (int id = t; id < tot; id += 256){
    int r = id / IN, k = id - r*IN;
    int row = row0 + r;
    hs[r][k] = (row < N) ? h[row*ldh + k] : 0.f;
  }
  float2 acc[8];
  #pragma unroll
  for (int j = 0; j < 8; j++) acc[j] = make_float2(0.f, 0.f);
  for (int kb = 0; kb < IN; kb += 64){
    __syncthreads();
    for (int id = t; id < 64*64; id += 256){
      int kk = id >> 6, l = id & 63;
      int k = kb + kk;
      Wp[kk][l] = make_float2(Wa[k*ldw + l], Wb[k*ldw + l]);
    }
    __syncthreads();
    for (int kk = 0; kk < 64; kk += 4){
      int k = kb + kk;
      float4 hv[8];
      #pragma unroll
      for (int j = 0; j < 8; j++) hv[j] = *(const float4*)&hs[wid*8 + j][k];
      #pragma unroll
      for (int u = 0; u < 4; u++){
        float2 wv = Wp[kk + u][lane];
        #pragma unroll
        for (int j = 0; j < 8; j++){
          float hvu = (&hv[j].x)[u];
          acc[j].x += hvu * wv.x;
          acc[j].y += hvu * wv.y;
        }
      }
    }
  }
  #pragma unroll
  for (int j = 0; j < 8; j++){
    int row = row0 + wid*8 + j;
    if (row < N){
      fhb[(size_t)row*128 + lane]      = f2bf(acc[j].x);
      fhb[(size_t)row*128 + 64 + lane] = f2bf(acc[j].y);
    }
  }
}

// elr[n][4] = {el_h0, el_h1, er_h0, er_h1}; one wave per node; fh in bf16.
__global__ void k_elr(const unsigned short* __restrict__ fhb, const float* __restrict__ al,
                      const float* __restrict__ ar, int H, float* __restrict__ elr, int N){
  int t = blockIdx.x*blockDim.x + threadIdx.x;
  int lane = t & 63, n = t >> 6;
  if (n >= N) return;
  float pel = 0.f, per = 0.f;
  if (lane*2 < H*64){
    unsigned int w = ((const unsigned int*)(fhb + (size_t)n*128))[lane];  // cols 2l,2l+1
    float vx = bf2f((unsigned short)(w & 0xffffu));
    float vy = bf2f((unsigned short)(w >> 16));
    float2 a = ((const float2*)al)[lane];
    float2 r = ((const float2*)ar)[lane];
    pel = vx*a.x + vy*a.y;
    per = vx*r.x + vy*r.y;
  }
  #pragma unroll
  for (int off = 16; off >= 1; off >>= 1){  // reduce within 32-lane halves (= heads)
    pel += __shfl_xor(pel, off, 64);
    per += __shfl_xor(per, off, 64);
  }
  if (lane == 0)  { elr[n*4+0] = pel; elr[n*4+2] = per; }
  if (lane == 32) { elr[n*4+1] = pel; elr[n*4+3] = per; }
}

// One wave per dst node. Pass 1: online softmax (m,d). Pass 2: weighted gather,
// readlane broadcast + 8-deep load pipelining.
__global__ __launch_bounds__(256) void k_agg(
    const unsigned short* __restrict__ fhb, const float* __restrict__ elr,
    const int* __restrict__ row_ptr, const int* __restrict__ ssrc,
    const float* __restrict__ bias, const float* __restrict__ res,
    int H, int act, int res_from_fh,
    float* __restrict__ out, int out_ld, int N){
  int lane = threadIdx.x & 63, wid = threadIdx.x >> 6;
  int n = blockIdx.x*4 + wid;
  if (n >= N) return;
  int beg = row_ptr[n], end = row_ptr[n+1];
  float er0 = elr[n*4+2], er1 = elr[n*4+3];

  // pass 1: per-lane online softmax, then cross-lane merge
  float m0 = -1e30f, m1 = -1e30f, d0 = 0.f, d1 = 0.f;
  for (int i = beg + lane; i < end; i += 64){
    int s = ssrc[i];
    float2 el = *(const float2*)(elr + s*4);
    float e0 = lrelu(el.x + er0), e1 = lrelu(el.y + er1);
    float nm0 = fmaxf(m0, e0);
    d0 = d0*__expf(m0 - nm0) + __expf(e0 - nm0); m0 = nm0;
    float nm1 = fmaxf(m1, e1);
    d1 = d1*__expf(m1 - nm1) + __expf(e1 - nm1); m1 = nm1;
  }
  #pragma unroll
  for (int off = 32; off >= 1; off >>= 1){
    float mo0 = __shfl_xor(m0, off, 64), do0 = __shfl_xor(d0, off, 64);
    float nm0 = fmaxf(m0, mo0);
    d0 = d0*__expf(m0 - nm0) + do0*__expf(mo0 - nm0); m0 = nm0;
    float mo1 = __shfl_xor(m1, off, 64), do1 = __shfl_xor(d1, off, 64);
    float nm1 = fmaxf(m1, mo1);
    d1 = d1*__expf(m1 - nm1) + do1*__expf(mo1 - nm1); m1 = nm1;
  }
  float rd0 = d0 > 0.f ? 1.f/d0 : 0.f;
  float rd1 = d1 > 0.f ? 1.f/d1 : 0.f;

  // pass 2: alpha-weighted gather of bf16 rows, 8 loads in flight
  float ax = 0.f, ay = 0.f;
  for (int base = beg; base < end; base += 64){
    int i = base + lane;
    int s = 0; float a0 = 0.f, a1 = 0.f;
    if (i < end){
      s = ssrc[i];
      float2 el = *(const float2*)(elr + s*4);
      a0 = __expf(lrelu(el.x + er0) - m0) * rd0;
      a1 = __expf(lrelu(el.y + er1) - m1) * rd1;
    }
    int cnt  = min(64, end - base);
    int cnt8 = (cnt + 7) & ~7;          // pad lanes have a=0, s=0 -> contribute 0
    if (H == 2){
      for (int j0 = 0; j0 < cnt8; j0 += 8){
        unsigned int w[8]; float aj[8];
        #pragma unroll
        for (int u = 0; u < 8; u++){
          int sj = __builtin_amdgcn_readlane(s, j0 + u);      // SGPR: scalar addr calc
          w[u] = ((const unsigned int*)fhb)[(size_t)sj*64 + lane];
        }
        #pragma unroll
        for (int u = 0; u < 8; u++){
          float aj0 = rl_f(a0, j0 + u);
          float aj1 = rl_f(a1, j0 + u);
          aj[u] = (lane < 32) ? aj0 : aj1;   // cols 2l,2l+1: head = lane/32
        }
        #pragma unroll
        for (int u = 0; u < 8; u++){
          ax += bf2f((unsigned short)(w[u] & 0xffffu)) * aj[u];
          ay += bf2f((unsigned short)(w[u] >> 16))     * aj[u];
        }
      }
    } else {
      for (int j0 = 0; j0 < cnt8; j0 += 8){
        unsigned short w[8]; float aj[8];
        #pragma unroll
        for (int u = 0; u < 8; u++){
          int sj = __builtin_amdgcn_readlane(s, j0 + u);
          w[u] = fhb[(size_t)sj*128 + lane];
        }
        #pragma unroll
        for (int u = 0; u < 8; u++) aj[u] = rl_f(a0, j0 + u);
        #pragma unroll
        for (int u = 0; u < 8; u++) ax += bf2f(w[u]) * aj[u];
      }
    }
  }
  if (H == 2){
    int c0 = lane*2;
    float o0 = ax + bias[c0], o1 = ay + bias[c0+1];
    if (res){ o0 += res[n*128 + c0]; o1 += res[n*128 + c0+1]; }
    if (act){ o0 = o0 > 0.f ? o0 : expm1f(o0); o1 = o1 > 0.f ? o1 : expm1f(o1); }
    *(float2*)(out + n*out_ld + c0) = make_float2(o0, o1);
  } else {
    float o = ax + bias[lane];
    if (res_from_fh) o += bf2f(fhb[(size_t)n*128 + 64 + lane]);
    out[n*out_ld + lane] = o;
  }
}

extern "C" void kernel_launch(void* const* d_in, const int* in_sizes, int n_in,
                              void* d_out, int out_size, void* d_ws, size_t ws_size,
                              hipStream_t stream) {
  const int*   feat = (const int*)  d_in[0];
  const float* fv   = (const float*)d_in[1];
  const int*   src  = (const int*)  d_in[2];
  const int*   dst  = (const int*)  d_in[3];
  const float* emb  = (const float*)d_in[4];
  const float* W0   = (const float*)d_in[5];
  const float* al0  = (const float*)d_in[6];
  const float* ar0  = (const float*)d_in[7];
  const float* b0   = (const float*)d_in[8];
  const float* W1   = (const float*)d_in[9];
  const float* al1  = (const float*)d_in[10];
  const float* ar1  = (const float*)d_in[11];
  const float* b1   = (const float*)d_in[12];
  const float* W2   = (const float*)d_in[13];
  const float* al2  = (const float*)d_in[14];
  const float* ar2  = (const float*)d_in[15];
  const float* b2   = (const float*)d_in[16];
  const float* rW2  = (const float*)d_in[17];
  const int N = in_sizes[0] / 8;   // 50000
  const int E = in_sizes[2];       // 800000

  size_t off = 0;
  auto alloc = [&](size_t bytes) -> void* {
    void* p = (char*)d_ws + off;
    off = (off + bytes + 255) & ~(size_t)255;
    return p;
  };
  unsigned short* P1 = (unsigned short*)alloc((size_t)N*128*sizeof(unsigned short)); // fh bf16
  float* P2     = (float*)alloc((size_t)N*128*sizeof(float));
  float* P3     = (float*)alloc((size_t)N*128*sizeof(float));
  float* elr    = (float*)alloc((size_t)N*4*sizeof(float));
  int* row_ptr  = (int*)alloc((size_t)(N+1)*sizeof(int));
  int* counts   = (int*)alloc((size_t)2*N*sizeof(int));
  int* cursor   = counts + N;
  int* ssrc     = (int*)alloc((size_t)E*sizeof(int));
  int* bsum     = (int*)alloc(256*sizeof(int));
  float* h0     = P3;   // h0 (N*64) aliases P3; dead before P3 is written as h2

  int nb1 = (N + 255) / 256;
  // CSR build
  k_zero_i32<<<(2*N + 255)/256, 256, 0, stream>>>(counts, 2*N);
  k_hist<<<(E + 255)/256, 256, 0, stream>>>(dst, counts, E);
  k_scan_local<<<nb1, 256, 0, stream>>>(counts, row_ptr, bsum, N);
  k_scan_top<<<1, 256, 0, stream>>>(bsum, nb1);
  k_scan_fix<<<nb1, 256, 0, stream>>>(row_ptr, bsum, N);
  k_scatter<<<(E + 255)/256, 256, 0, stream>>>(src, dst, row_ptr, cursor, ssrc, E);
  // embedding gather (batch row 0 only)
  k_gather_h0<<<(N*64 + 255)/256, 256, 0, stream>>>(feat, fv, emb, h0, N);

  int gt = (N + 31)/32;
  int nagg = (N + 3)/4;
  // layer 0: in=64, H=2, no residual, elu
  k_gemm<<<gt, 256, 0, stream>>>(h0, 64, 64, W0, W0 + 64, 128, P1, N);
  k_elr<<<nagg, 256, 0, stream>>>(P1, al0, ar0, 2, elr, N);
  k_agg<<<nagg, 256, 0, stream>>>(P1, elr, row_ptr, ssrc, b0, nullptr, 2, 1, 0, P2, 128, N);
  // layer 1: in=128, H=2, identity residual, elu
  k_gemm<<<gt, 256, 0, stream>>>(P2, 128, 128, W1, W1 + 64, 128, P1, N);
  k_elr<<<nagg, 256, 0, stream>>>(P1, al1, ar1, 2, elr, N);
  k_agg<<<nagg, 256, 0, stream>>>(P1, elr, row_ptr, ssrc, b1, P2, 2, 1, 0, P3, 128, N);
  // layer 2: in=128, H=1, projected residual (fh cols 64..127 = h@resW2), no act
  k_gemm<<<gt, 256, 0, stream>>>(P3, 128, 128, W2, rW2, 64, P1, N);
  k_elr<<<nagg, 256, 0, stream>>>(P1, al2, ar2, 1, elr, N);
  k_agg<<<nagg, 256, 0, stream>>>(P1, elr, row_ptr, ssrc, b2, nullptr, 1, 0, 1, (float*)d_out, 64, N);
}